// Round 19
// baseline (330.184 us; speedup 1.0000x reference)
//
#include <hip/hip_runtime.h>
#include <hip/hip_bf16.h>

#define DINLINE __device__ __forceinline__

typedef short short8 __attribute__((ext_vector_type(8)));
typedef float f32x4 __attribute__((ext_vector_type(4)));
typedef unsigned short u16;

DINLINE u16 f2b(float f) {
  __hip_bfloat16 h = __float2bfloat16(f);
  return *reinterpret_cast<u16*>(&h);
}
DINLINE float b2f(u16 u) {
  __hip_bfloat16 h = *reinterpret_cast<__hip_bfloat16*>(&u);
  return __bfloat162float(h);
}

DINLINE void gload16(const u16* g, u16* l) {
  __builtin_amdgcn_global_load_lds((const __attribute__((address_space(1))) void*)g,
                                   (__attribute__((address_space(3))) void*)l, 16, 0, 0);
}

DINLINE void wave_red2(float& s, float& s2) {
  for (int o = 32; o > 0; o >>= 1) { s += __shfl_down(s, o); s2 += __shfl_down(s2, o); }
}

// grid-stride float4 copy of gx span [f4lo, f4hi) into out
DINLINE void do_copy(float* out, const float* gx, long f4lo, long f4hi, int cb, int ncb) {
  const float4* s = (const float4*)gx;
  float4* d = (float4*)out;
  for (long i = f4lo + (long)cb * 256 + threadIdx.x; i < f4hi; i += (long)ncb * 256)
    d[i] = s[i];
}

// ---------------- A-source functors ----------------

struct RowA {
  const u16* A; int physW;
  struct RS { const u16* base; };
  DINLINE RS row(long p) const { return { A + p * (long)physW }; }
  DINLINE const u16* ptr(const RS& rs, int kk) const { return rs.base + (kk << 6); }
};
struct TriA {  // [hi|lo] phys; logical role r = kk%3: (hi, lo, hi)
  const u16* A; int physW; int nhi;
  struct RS { const u16* base; };
  DINLINE RS row(long p) const { return { A + p * (long)physW }; }
  DINLINE const u16* ptr(const RS& rs, int kk) const {
    int c = (int)(((unsigned)kk * 171u) >> 9), r = kk - 3 * c;
    return rs.base + (((r == 1 ? nhi : 0) + c) << 6);
  }
};
struct ShiftVA {  // V conv rows over sel [b][256][1024]
  const u16* src; const u16* zp;
  struct RS { int y, x; const u16* bbase; };
  DINLINE RS row(long p) const {
    int b = (int)(p >> 8), ps = (int)p & 255;
    return { ps >> 4, ps & 15, src + ((long)b << 18) };
  }
  DINLINE const u16* ptr(const RS& rs, int kk) const {
    int c = (int)(((unsigned)kk * 57u) >> 9), s = kk - 9 * c;
    int sy = (s * 11) >> 5, sx = s - sy * 3;
    int yy = rs.y + sy - 1, xx = rs.x + sx - 1;
    bool ok = ((unsigned)yy < 16u) & ((unsigned)xx < 16u);
    return ok ? rs.bbase + (((yy << 4) + xx) << 10) + (c << 6) : zp;
  }
};
struct Shift9A {  // SGSB conv rows over ac [b][128][1024] (9x9 spatial)
  const u16* src; const u16* zp;
  struct RS { int y, x; const u16* bbase; int pin; };
  DINLINE RS row(long p) const {
    int pi = (int)p;
    int b = pi / 81, pp = pi - b * 81;
    int pin = pi < 2592 ? 1 : 0;
    if (b > 31) b = 31;
    return { pp / 9, pp % 9, src + ((long)b << 17), pin };
  }
  DINLINE const u16* ptr(const RS& rs, int kk) const {
    int c = (int)(((unsigned)kk * 57u) >> 9), s = kk - 9 * c;
    int sy = (s * 11) >> 5, sx = s - sy * 3;
    int yy = rs.y + sy - 1, xx = rs.x + sx - 1;
    bool ok = rs.pin && ((unsigned)yy < 9u) && ((unsigned)xx < 9u);
    return ok ? rs.bbase + ((yy * 9 + xx) << 10) + (c << 6) : zp;
  }
};

// ---------------- B-source functors ----------------

struct RowB {  // batch = by>>1 for 64-row tiles in 128-row batches
  const u16* B; int physW; long bstride;
  struct RS { const u16* base; };
  DINLINE RS row(int by, long j) const { return { B + ((long)(by >> 1) * bstride + j) * physW }; }
  DINLINE const u16* ptr(const RS& rs, int kk) const { return rs.base + (kk << 6); }
};
struct TriB {  // [hi|lo] phys; role r: (hi, hi, lo)
  const u16* B; int physW; int nhi; long bstride;
  struct RS { const u16* base; };
  DINLINE RS row(int by, long j) const { return { B + ((long)(by >> 1) * bstride + j) * physW }; }
  DINLINE const u16* ptr(const RS& rs, int kk) const {
    int c = (int)(((unsigned)kk * 171u) >> 9), r = kk - 3 * c;
    return rs.base + (((r == 2 ? nhi : 0) + c) << 6);
  }
};
struct ShiftWB {  // conv weights [N][9216] shift-major
  const u16* W;
  struct RS { const u16* base; };
  DINLINE RS row(int, long j) const { return { W + j * 9216 }; }
  DINLINE const u16* ptr(const RS& rs, int kk) const {
    int c = (int)(((unsigned)kk * 57u) >> 9), s = kk - 9 * c;
    return rs.base + (s << 10) + (c << 6);
  }
};

// ---------------- epilogues ----------------

struct EpiHiLo {
  u16* o; const float* bias;
  DINLINE void operator()(long p, int j, float v) const {
    v += bias[j];
    u16 hi = f2b(v), lo = f2b(v - b2f(hi));
    u16* q = o + p * 640 + j;
    q[0] = hi; q[320] = lo;
  }
};
struct EpiHiLoP {
  u16* o; const float* bias;
  DINLINE void operator()(int, long p, int j, float v) const {
    if (j >= 320) return;
    v += bias[j];
    u16 hi = f2b(v), lo = f2b(v - b2f(hi));
    u16* q = o + p * 640 + j;
    q[0] = hi; q[320] = lo;
  }
};
struct EpiLog {
  float* attn;
  DINLINE void operator()(long p, int j, float v) const {
    int b = (int)(p >> 7), i = (int)p & 127;
    if (i < 81) attn[((long)b * 81 + i) * 256 + j] = v;
  }
};
struct EpiXaAc {
  float* xa; u16* ac;
  DINLINE void operator()(long p, int j, float v) const {
    int b = (int)(p >> 7), i = (int)p & 127;
    if (j < 320) {
      xa[((long)b * 128 + i) * 320 + j] = v;
    } else {
      ac[((long)b * 128 + i) * 1024 + (j - 320)] = f2b(v);
    }
  }
};
struct EpiPart {
  float* buf; long pstride; int jw;
  DINLINE void operator()(int part, long p, int j, float v) const {
    buf[(long)part * pstride + p * (long)jw + j] = v;
  }
};

// ---------------- 64x64 4-wave pipelined MFMA GEMM body (lds: 16384 u16) ----------------

template <class AS, class BS, class EPI>
DINLINE void gemm_pipe_body(u16* lds, AS a, BS bsrc, int gy, int nch, EPI epi,
                            int subN, int bid) {
  const int q = subN >> 3, r8 = subN & 7;
  const int j8 = bid & 7, pos = bid >> 3;
  const int lid = (j8 < r8) ? j8 * (q + 1) + pos : r8 * (q + 1) + (j8 - r8) * q + pos;
  const int by = lid % gy, bx = lid / gy;

  const int tid = threadIdx.x;
  const int w = tid >> 6, lane = tid & 63;
  const int wm = w >> 1, wn = w & 1;
  const long p0 = (long)by * 64;
  const int j0 = bx * 64;

  const int r0 = tid >> 3;
  const int csw = (((lane & 7) ^ (lane >> 3)) << 3);
  auto rsA0 = a.row(p0 + r0);
  auto rsA1 = a.row(p0 + r0 + 32);
  auto rsB0 = bsrc.row(by, j0 + r0);
  auto rsB1 = bsrc.row(by, j0 + r0 + 32);
  u16* lA0 = lds + w * 512;
  u16* lA1 = lds + 2048 + w * 512;
  u16* lB0 = lds + 8192 + w * 512;
  u16* lB1 = lds + 8192 + 2048 + w * 512;

  f32x4 acc[2][2];
#pragma unroll
  for (int x = 0; x < 2; ++x)
#pragma unroll
    for (int y = 0; y < 2; ++y) acc[x][y] = (f32x4){0.f, 0.f, 0.f, 0.f};

  const int fr = lane & 15, fs = lane >> 4, fx = lane & 7;
  const int arow0 = (wm * 32 + fr) * 64;
  const int brow0 = (wn * 32 + fr) * 64;

  gload16(a.ptr(rsA0, 0) + csw, lA0);
  gload16(a.ptr(rsA1, 0) + csw, lA1);
  gload16(bsrc.ptr(rsB0, 0) + csw, lB0);
  gload16(bsrc.ptr(rsB1, 0) + csw, lB1);

  for (int kk = 0; kk < nch; ++kk) {
    const int cur = kk & 1;
    if (kk + 1 < nch) {
      const int nxt = cur ^ 1;
      gload16(a.ptr(rsA0, kk + 1) + csw, lA0 + nxt * 4096);
      gload16(a.ptr(rsA1, kk + 1) + csw, lA1 + nxt * 4096);
      gload16(bsrc.ptr(rsB0, kk + 1) + csw, lB0 + nxt * 4096);
      gload16(bsrc.ptr(rsB1, kk + 1) + csw, lB1 + nxt * 4096);
      asm volatile("s_waitcnt vmcnt(4)" ::: "memory");
    } else {
      asm volatile("s_waitcnt vmcnt(0)" ::: "memory");
    }
    __builtin_amdgcn_s_barrier();
    __builtin_amdgcn_sched_barrier(0);
    short8 af[2][2], bf[2][2];
#pragma unroll
    for (int fm = 0; fm < 2; ++fm)
#pragma unroll
      for (int kh = 0; kh < 2; ++kh) {
        int slot = ((((kh << 2) | fs) ^ fx) << 3);
        af[fm][kh] = *(const short8*)(lds + cur * 4096 + arow0 + fm * 1024 + slot);
      }
#pragma unroll
    for (int fn = 0; fn < 2; ++fn)
#pragma unroll
      for (int kh = 0; kh < 2; ++kh) {
        int slot = ((((kh << 2) | fs) ^ fx) << 3);
        bf[fn][kh] = *(const short8*)(lds + 8192 + cur * 4096 + brow0 + fn * 1024 + slot);
      }
#pragma unroll
    for (int kh = 0; kh < 2; ++kh)
#pragma unroll
      for (int fm = 0; fm < 2; ++fm)
#pragma unroll
        for (int fn = 0; fn < 2; ++fn)
          acc[fm][fn] = __builtin_amdgcn_mfma_f32_16x16x32_bf16(af[fm][kh], bf[fn][kh], acc[fm][fn], 0, 0, 0);
    __builtin_amdgcn_sched_barrier(0);
    __builtin_amdgcn_s_barrier();
  }

  const long ip = p0 + wm * 32 + fs * 4;
  const int jb = j0 + wn * 32 + fr;
#pragma unroll
  for (int fm = 0; fm < 2; ++fm)
#pragma unroll
    for (int fn = 0; fn < 2; ++fn)
#pragma unroll
      for (int rr = 0; rr < 4; ++rr)
        epi(ip + fm * 16 + rr, jb + fn * 16, acc[fm][fn][rr]);
}

// ------- 128xN 4-wave m97-structure MFMA GEMM body; tile N = NF*32 ----------

template <int NF, class AS, class BS, class EPI>
DINLINE void gemm128_body(u16* lds, AS a, BS bsrc, int gy, int gp, int nchw, EPI epi,
                          int subN, int bid, int j0base) {
  const int q = subN >> 3, r8 = subN & 7;
  const int j8 = bid & 7, pos = bid >> 3;
  const int lid = (j8 < r8) ? j8 * (q + 1) + pos : r8 * (q + 1) + (j8 - r8) * q + pos;
  const int gyp = gy * gp;
  const int bx = lid / gyp;
  const int rem = lid - bx * gyp;
  const int by = rem % gy;
  const int part = rem / gy;
  const int k0 = part * nchw;

  const int tid = threadIdx.x;
  const int w = tid >> 6, lane = tid & 63;
  const int wm = w >> 1, wn = w & 1;
  const long p0 = (long)by * 128;
  const int j0 = j0base + bx * (NF * 32);

  const int r0 = tid >> 3;
  const int csw = (((lane & 7) ^ (lane >> 3)) << 3);
  typename AS::RS rsA[4];
  typename BS::RS rsB[NF];
#pragma unroll
  for (int i = 0; i < 4; ++i) rsA[i] = a.row(p0 + r0 + 32 * i);
#pragma unroll
  for (int i = 0; i < NF; ++i) rsB[i] = bsrc.row(by, (long)j0 + r0 + 32 * i);

  f32x4 acc[4][NF];
#pragma unroll
  for (int x = 0; x < 4; ++x)
#pragma unroll
    for (int y = 0; y < NF; ++y) acc[x][y] = (f32x4){0.f, 0.f, 0.f, 0.f};

  const int fr = lane & 15, fs = lane >> 4, fx = lane & 7;

  for (int kk = 0; kk < nchw; ++kk) {
    __syncthreads();
#pragma unroll
    for (int i = 0; i < 4; ++i)
      gload16(a.ptr(rsA[i], k0 + kk) + csw, lds + (i * 32 + w * 8) * 64);
#pragma unroll
    for (int i = 0; i < NF; ++i)
      gload16(bsrc.ptr(rsB[i], k0 + kk) + csw, lds + 8192 + (i * 32 + w * 8) * 64);
    __syncthreads();
#pragma unroll
    for (int kh = 0; kh < 2; ++kh) {
      const int slot = ((((kh << 2) | fs) ^ fx) << 3);
      short8 af[4], bf[NF];
#pragma unroll
      for (int i = 0; i < 4; ++i)
        af[i] = *(const short8*)(lds + (wm * 64 + i * 16 + fr) * 64 + slot);
#pragma unroll
      for (int i = 0; i < NF; ++i)
        bf[i] = *(const short8*)(lds + 8192 + (wn * (NF * 16) + i * 16 + fr) * 64 + slot);
#pragma unroll
      for (int fm = 0; fm < 4; ++fm)
#pragma unroll
        for (int fn = 0; fn < NF; ++fn)
          acc[fm][fn] = __builtin_amdgcn_mfma_f32_16x16x32_bf16(af[fm], bf[fn], acc[fm][fn], 0, 0, 0);
    }
  }

  const long ip = p0 + wm * 64 + fs * 4;
  const int jb = j0 + wn * (NF * 16) + fr;
#pragma unroll
  for (int fm = 0; fm < 4; ++fm)
#pragma unroll
    for (int fn = 0; fn < NF; ++fn)
#pragma unroll
      for (int rr = 0; rr < 4; ++rr)
        epi(part, ip + fm * 16 + rr, jb + fn * 16, acc[fm][fn][rr]);
}

// ---------------- merged prep kernel 0: ctx_stats | roi | wprep ----------------
__global__ void k_prep0(const float* __restrict__ ctx, const int* __restrict__ cond,
                        const float* __restrict__ gx, const float* __restrict__ bbox,
                        const float* __restrict__ Wk, const float* __restrict__ Wq,
                        const float* __restrict__ Wv, const float* __restrict__ Wsg,
                        const float* __restrict__ Wsb,
                        float* __restrict__ cmean, float* __restrict__ stats,
                        float* __restrict__ roix, u16* __restrict__ oK, u16* __restrict__ oQ,
                        u16* __restrict__ Wv_r, u16* __restrict__ Wsgsb) {
  __shared__ float shf[4][2];
  __shared__ float cp[8][32];
  __shared__ float cm32[32];
  __shared__ int iy0[9], iy1[9], ix0[9], ix1[9];
  __shared__ float fly[9], flx[9];
  __shared__ u16 l[9216];
  int bid = blockIdx.x;
  int tid = threadIdx.x;

  if (bid < 1024) {
    int b = bid >> 5, g = bid & 31;
    const float* src = ctx + (size_t)b * 262144 + g * 32;
    int c = tid & 31, tg = tid >> 5;
    float cs = 0.f, s = 0.f, s2 = 0.f;
#pragma unroll 4
    for (int k = 0; k < 32; ++k) {
      int t = tg + k * 8;
      float v = src[(size_t)t * 1024 + c];
      cs += v; s += v; s2 += v * v;
    }
    cp[tg][c] = cs;
    wave_red2(s, s2);
    int lane = tid & 63, w = tid >> 6;
    if (lane == 0) { shf[w][0] = s; shf[w][1] = s2; }
    __syncthreads();
    if (tid < 32) {
      float colsum = 0.f;
#pragma unroll
      for (int k = 0; k < 8; ++k) colsum += cp[k][tid];
      float mv = colsum * (1.f / 256.f);
      cmean[b * 1024 + g * 32 + tid] = mv;
      cm32[tid] = mv;
    }
    __syncthreads();
    if (tid == 0) {
      float m, var;
      if (cond[b]) {
        float ts = shf[0][0] + shf[1][0] + shf[2][0] + shf[3][0];
        float ts2 = shf[0][1] + shf[1][1] + shf[2][1] + shf[3][1];
        m = ts * (1.f / 8192.f);
        var = ts2 * (1.f / 8192.f) - m * m;
      } else {
        float ms = 0.f, ms2 = 0.f;
#pragma unroll
        for (int k = 0; k < 32; ++k) { ms += cm32[k]; ms2 += cm32[k] * cm32[k]; }
        m = ms * (1.f / 32.f);
        var = ms2 * (1.f / 32.f) - m * m;
      }
      stats[bid * 2] = m;
      stats[bid * 2 + 1] = 1.f / sqrtf(var + 1e-6f);
    }
    return;
  }
  if (bid < 1056) {
    int b = bid - 1024;
    int t = tid;
    if (t < 9) {
      float x1 = bbox[b * 4 + 0], y1 = bbox[b * 4 + 1], x2 = bbox[b * 4 + 2], y2 = bbox[b * 4 + 3];
      float rw = fmaxf(x2 - x1, 1.f), rh = fmaxf(y2 - y1, 1.f);
      float ctr = ((float)t + 0.5f) / 9.0f;
      float yc = fminf(fmaxf(y1 + ctr * rh, 0.f), 63.f);
      int y0 = (int)floorf(yc);
      iy0[t] = y0; iy1[t] = min(y0 + 1, 63); fly[t] = yc - (float)y0;
      float xc = fminf(fmaxf(x1 + ctr * rw, 0.f), 63.f);
      int x0 = (int)floorf(xc);
      ix0[t] = x0; ix1[t] = min(x0 + 1, 63); flx[t] = xc - (float)x0;
    }
    __syncthreads();
    for (int idx = t; idx < 320 * 81; idx += 256) {
      int c = idx / 81, p = idx - c * 81;
      int py = p / 9, px = p - py * 9;
      const float* img = gx + ((size_t)b * 320 + c) * 4096;
      float ly = fly[py], lx = flx[px];
      float v00 = img[iy0[py] * 64 + ix0[px]];
      float v01 = img[iy0[py] * 64 + ix1[px]];
      float v10 = img[iy1[py] * 64 + ix0[px]];
      float v11 = img[iy1[py] * 64 + ix1[px]];
      roix[((size_t)b * 320 + c) * 81 + p] =
          v00 * (1.f - ly) * (1.f - lx) + v01 * (1.f - ly) * lx + v10 * ly * (1.f - lx) + v11 * ly * lx;
    }
    return;
  }
  int bid2 = bid - 1056;
  if (bid2 < 1536) {
    int i = bid2 * 256 + tid;
    int c = i >> 10, d = i & 1023;
    float v = (i < 327680) ? Wk[i] : 0.f;
    u16 hi = f2b(v), lo = f2b(v - b2f(hi));
    u16* p = oK + (size_t)c * 2048 + d;
    p[0] = hi; p[1024] = lo;
    return;
  }
  if (bid2 < 2016) {
    int i = (bid2 - 1536) * 256 + tid;
    if (i >= 122880) return;
    int c = i / 384, k = i - c * 384;
    float v = (k < 322) ? Wq[c * 322 + k] : 0.f;
    u16 hi = f2b(v), lo = f2b(v - b2f(hi));
    u16* p = oQ + (size_t)c * 768 + k;
    p[0] = hi; p[384] = lo;
    return;
  }
  int cc = bid2 - 2016;
  const float* src = nullptr; u16* dst;
  if (cc < 384) { dst = Wv_r + (size_t)cc * 9216; if (cc < 320) src = Wv + (size_t)cc * 9216; }
  else if (cc < 704) { src = Wsg + (size_t)(cc - 384) * 9216; dst = Wsgsb + (size_t)(cc - 384) * 9216; }
  else { src = Wsb + (size_t)(cc - 704) * 9216; dst = Wsgsb + (size_t)(320 + cc - 704) * 9216; }
  if (src == nullptr) {
    for (int i = tid; i < 9216; i += 256) dst[i] = 0;
    return;
  }
  for (int i = tid; i < 9216; i += 256) l[i] = f2b(src[i]);
  __syncthreads();
  for (int i = tid; i < 9216; i += 256) {
    int r = i >> 10, d = i & 1023;
    dst[i] = l[d * 9 + r];
  }
}

// ---------------- merged prep kernel 1: ctx_prep (0..2047) | stats810 (2048..3071) ------
__global__ __launch_bounds__(256) void k_prep1(
    const float* __restrict__ ctx, const float* __restrict__ cmean,
    const float* __restrict__ st, const float* __restrict__ cng,
    const float* __restrict__ cnb, const int* __restrict__ cond,
    u16* __restrict__ sel, u16* __restrict__ bvc, u16* __restrict__ cn2,
    const float* __restrict__ roix, float* __restrict__ lnst) {
  __shared__ u16 tile[64][66];
  __shared__ float sh[4][2];
  int bid = blockIdx.x;
  if (bid < 2048) {
    int b = bid >> 6;
    int d0 = ((bid >> 2) & 15) * 64;
    int t0 = (bid & 3) * 64;
    bool cf = cond[b] != 0;
#pragma unroll
    for (int q = 0; q < 16; ++q) {
      int idx = q * 256 + threadIdx.x;
      int r = idx >> 6, c = idx & 63;
      int t = t0 + r, d = d0 + c;
      float v = cf ? ctx[((size_t)b * 256 + t) * 1024 + d] : cmean[b * 1024 + d];
      u16 sv = f2b(v);
      sel[((size_t)b * 256 + t) * 1024 + d] = sv;
      tile[r][c] = sv;
      int gi = (b << 5) + (d >> 5);
      float nv = (v - st[gi * 2]) * st[gi * 2 + 1] * cng[d] + cnb[d];
      u16 hi = f2b(nv);
      u16 lo = f2b(nv - b2f(hi));
      size_t rbase = ((size_t)b * 256 + t) * 2048;
      cn2[rbase + d] = hi;
      cn2[rbase + 1024 + d] = lo;
    }
    __syncthreads();
#pragma unroll
    for (int q = 0; q < 16; ++q) {
      int idx = q * 256 + threadIdx.x;
      int r = idx >> 6, c = idx & 63;
      bvc[((size_t)b * 1344 + 320 + d0 + r) * 256 + t0 + c] = tile[c][r];
    }
    return;
  }
  int bg = bid - 2048;
  const float* p = roix + (size_t)bg * 810;
  float s = 0.f, s2 = 0.f;
  for (int i = threadIdx.x; i < 810; i += 256) { float v = p[i]; s += v; s2 += v * v; }
  wave_red2(s, s2);
  int lane = threadIdx.x & 63, w = threadIdx.x >> 6;
  if (lane == 0) { sh[w][0] = s; sh[w][1] = s2; }
  __syncthreads();
  if (threadIdx.x == 0) {
    s = sh[0][0] + sh[1][0] + sh[2][0] + sh[3][0];
    s2 = sh[0][1] + sh[1][1] + sh[2][1] + sh[3][1];
    float m = s * (1.f / 810.f);
    float var = s2 * (1.f / 810.f) - m * m;
    lnst[bg * 2] = m;
    lnst[bg * 2 + 1] = 1.f / sqrtf(var + 1e-6f);
  }
}

// Aq2 [4096][hi(384)|lo(384)]
__global__ void k_aq2(const float* __restrict__ roix, const float* __restrict__ st,
                      const float* __restrict__ lng, const float* __restrict__ lnb,
                      const float* __restrict__ ind, u16* __restrict__ o) {
  int i = blockIdx.x * 256 + threadIdx.x;
  if (i >= 32 * 128 * 384) return;
  int b = i / (128 * 384), rem = i - b * (128 * 384);
  int row = rem / 384, k = rem - row * 384;
  float v = 0.f;
  if (row < 81) {
    if (k < 320) {
      float x = roix[((size_t)b * 320 + k) * 81 + row];
      int gi = (b << 5) + k / 10;
      v = (x - st[gi * 2]) * st[gi * 2 + 1] * lng[k] + lnb[k];
    } else if (k < 322) v = ind[b * 2 + (k - 320)];
  }
  u16 hi = f2b(v);
  u16 lo = f2b(v - b2f(hi));
  u16* p = o + ((size_t)b * 128 + row) * 768 + k;
  p[0] = hi; p[384] = lo;
}

// -------- packed GEMMs: Kfull(0..127) | Knarrow(128..191) | Vfull(192..447) |
//          Vnarrow(448..575) | Q(576..895)
__global__ __launch_bounds__(256, 3) void k_gemms(
    const u16* __restrict__ cn2, const u16* __restrict__ Wk2, u16* __restrict__ k2,
    const float* __restrict__ bk,
    const u16* __restrict__ sel, const u16* __restrict__ Wv_r, const u16* __restrict__ zpage,
    float* __restrict__ partV,
    const u16* __restrict__ Aq2, const u16* __restrict__ Wq2, u16* __restrict__ q2,
    const float* __restrict__ bq) {
  __shared__ u16 lds[16384];
  int bid = blockIdx.x;
  if (bid < 128) {
    gemm128_body<4>(lds, TriA{cn2, 2048, 16}, TriB{Wk2, 2048, 16, 0}, 64, 1, 48,
                    EpiHiLoP{k2, bk}, 128, bid, 0);
  } else if (bid < 192) {
    gemm128_body<2>(lds, TriA{cn2, 2048, 16}, TriB{Wk2, 2048, 16, 0}, 64, 1, 48,
                    EpiHiLoP{k2, bk}, 64, bid - 128, 256);
  } else if (bid < 448) {
    gemm128_body<4>(lds, ShiftVA{sel, zpage}, ShiftWB{Wv_r}, 64, 2, 72,
                    EpiPart{partV, (long)8192 * 384, 384}, 256, bid - 192, 0);
  } else if (bid < 576) {
    gemm128_body<2>(lds, ShiftVA{sel, zpage}, ShiftWB{Wv_r}, 64, 2, 72,
                    EpiPart{partV, (long)8192 * 384, 384}, 128, bid - 448, 256);
  } else {
    gemm_pipe_body(lds, TriA{Aq2, 768, 6}, TriB{Wq2, 768, 6, 0}, 64, 18,
                   EpiHiLo{q2, bq}, 320, bid - 576);
  }
}

// ---------------- packed mid: sumv_t (0..639) | logits (640..895) | copies (896..1407) ---
__global__ __launch_bounds__(256, 4) void k_mid(
    const float* __restrict__ partV, const float* __restrict__ bv, u16* __restrict__ bvc,
    const u16* __restrict__ q2, const u16* __restrict__ k2, float* __restrict__ attn,
    const float* __restrict__ gx, float* __restrict__ outf) {
  __shared__ u16 lds[16384];
  int bid = blockIdx.x;
  if (bid < 640) {
    int b = bid / 20, rem = bid - b * 20;
    int t0 = (rem & 3) * 64, j0 = (rem >> 2) * 64;
    const long pstride = (long)8192 * 384;
#pragma unroll
    for (int q = 0; q < 16; ++q) {
      int idx = q * 256 + threadIdx.x;
      int r = idx >> 6, c = idx & 63;
      long p = (long)b * 256 + t0 + r;
      const float* src = partV + p * 384 + j0 + c;
      float v = src[0] + src[pstride] + bv[j0 + c];
      lds[r * 66 + c] = f2b(v);
    }
    __syncthreads();
#pragma unroll
    for (int q = 0; q < 16; ++q) {
      int idx = q * 256 + threadIdx.x;
      int r = idx >> 6, c = idx & 63;
      bvc[((long)b * 1344 + j0 + r) * 256 + t0 + c] = lds[c * 66 + r];
    }
    return;
  }
  if (bid < 896) {
    gemm_pipe_body(lds, TriA{q2, 640, 5}, TriB{k2, 640, 5, 256}, 64, 15,
                   EpiLog{attn}, 256, bid - 640);
    return;
  }
  // copies of dead-after-k_gemms spans (+ always-dead)
  int cb = bid - 896;
  do_copy(outf, gx, 0, 1048576, cb, 512);          // sel [0, 16,777,216)
  do_copy(outf, gx, 4145152, 4915200, cb, 512);    // cn2-tail+Aq2 [66,322,432, 78,643,200)
  do_copy(outf, gx, 6553600, 7258624, cb, 512);    // gap+Wk2+Wq2+Wv_r-main [104,857,600, 116,137,984)
  do_copy(outf, gx, 9970176, 10485760, cb, 512);   // tail gap [159,522,816, 167,772,160)
}

__global__ void k_softmax2(float* __restrict__ attn, u16* __restrict__ attn_bf) {
  int i = blockIdx.x, b = blockIdx.y;
  int t = threadIdx.x;
  if (i >= 81) { attn_bf[((size_t)b * 128 + i) * 256 + t] = 0; return; }
  float* p = attn + ((size_t)b * 81 + i) * 256;
  float v = p[t];
  float m = v;
  for (int o = 32; o > 0; o >>= 1) m = fmaxf(m, __shfl_down(m, o));
  __shared__ float sm[4], ss[4];
  if ((t & 63) == 0) sm[t >> 6] = m;
  __syncthreads();
  m = fmaxf(fmaxf(sm[0], sm[1]), fmaxf(sm[2], sm[3]));
  float e = expf(v - m);
  float s = e;
  for (int o = 32; o > 0; o >>= 1) s += __shfl_down(s, o);
  if ((t & 63) == 0) ss[t >> 6] = s;
  __syncthreads();
  s = ss[0] + ss[1] + ss[2] + ss[3];
  float r = e / s;
  p[t] = r;
  attn_bf[((size_t)b * 128 + i) * 256 + t] = f2b(r);
}

// ---------------- packed attn GEMM: xa|ac (0..1343) | copies (1344..1855) ----------------
__global__ __launch_bounds__(256, 4) void k_attn(
    const u16* __restrict__ attn_bf, const u16* __restrict__ bvc,
    float* __restrict__ xa, u16* __restrict__ ac,
    const float* __restrict__ gx, float* __restrict__ outf) {
  __shared__ u16 lds[16384];
  int bid = blockIdx.x;
  if (bid < 1344) {
    gemm_pipe_body(lds, RowA{attn_bf, 256}, RowB{bvc, 256, 1344}, 64, 4,
                   EpiXaAc{xa, ac}, 1344, bid);
    return;
  }
  // copies of dead-after-k_mid spans
  int cb = bid - 1344;
  do_copy(outf, gx, 4915200, 5898240, cb, 512);    // k2+q2 [78,643,200, 94,371,840)
  do_copy(outf, gx, 8069632, 9642496, cb, 512);    // partV [129,114,112, 154,279,936)
}

// ---------------- packed post: stats_xa (0..1023) | SGSB (1024..1443) | copies (1444..1699)
__global__ __launch_bounds__(256, 3) void k_post(
    const float* __restrict__ xa, float* __restrict__ xast,
    const u16* __restrict__ ac_bf, const u16* __restrict__ zpage,
    const u16* __restrict__ Wsgsb, float* __restrict__ part_f,
    const float* __restrict__ gx, float* __restrict__ outf) {
  __shared__ u16 lds[16384];
  int bid = blockIdx.x;
  if (bid < 1024) {
    int b = bid >> 5, g = bid & 31;
    float s = 0.f, s2 = 0.f;
    for (int e = threadIdx.x; e < 810; e += 256) {
      int i = e / 10, cc = e - i * 10;
      float v = xa[((long)b * 128 + i) * 320 + g * 10 + cc];
      s += v; s2 += v * v;
    }
    wave_red2(s, s2);
    float* sh = (float*)lds;
    int lane = threadIdx.x & 63, w = threadIdx.x >> 6;
    if (lane == 0) { sh[w * 2] = s; sh[w * 2 + 1] = s2; }
    __syncthreads();
    if (threadIdx.x == 0) {
      s = sh[0] + sh[2] + sh[4] + sh[6];
      s2 = sh[1] + sh[3] + sh[5] + sh[7];
      float m = s * (1.f / 810.f);
      float var = s2 * (1.f / 810.f) - m * m;
      xast[bid * 2] = m;
      xast[bid * 2 + 1] = 1.f / sqrtf(var + 1e-5f);
    }
    return;
  }
  if (bid < 1444) {
    gemm128_body<4>(lds, Shift9A{ac_bf, zpage}, ShiftWB{Wsgsb}, 21, 4, 36,
                    EpiPart{part_f, (long)2688 * 640, 640}, 420, bid - 1024, 0);
    return;
  }
  // copies of dead-after-k_attn spans
  int cb = bid - 1444;
  do_copy(outf, gx, 1048576, 2424832, cb, 256);    // bvc [16,777,216, 38,797,312)
  do_copy(outf, gx, 5898240, 6029312, cb, 256);    // attn_bf [94,371,840, 96,468,992)
}

// fused SGSB sum + bias + gn(xa)*sg + sb -> xloc (0..2591) | copies (2592..2847)
__global__ void k_sum_sgsb(const float* __restrict__ buf, long pstride,
                           const float* __restrict__ bsg, const float* __restrict__ bsb,
                           const float* __restrict__ xa, const float* __restrict__ st,
                           float* __restrict__ xl,
                           const float* __restrict__ gx, float* __restrict__ outf) {
  __shared__ float sgb[640];
  __shared__ float ms[32], rss[32];
  long p = blockIdx.x;
  if (p >= 2592) {
    int cb = (int)p - 2592;
    do_copy(outf, gx, 6029312, 6553600, cb, 256);  // ac_bf [96,468,992, 104,857,600)
    do_copy(outf, gx, 7258624, 8069632, cb, 256);  // zpage+Wsgsb [116,137,984, 129,114,112)
    return;
  }
  int b = (int)(p / 81), pp = (int)(p - (long)b * 81);
  const float* src = buf + p * 640;
  for (int j = threadIdx.x; j < 640; j += 256) {
    float v = 0.f;
#pragma unroll
    for (int t = 0; t < 4; ++t) v += src[t * pstride + j];
    sgb[j] = v + (j < 320 ? bsg[j] : bsb[j - 320]);
  }
  if (threadIdx.x < 32) {
    ms[threadIdx.x] = st[(b * 32 + threadIdx.x) * 2];
    rss[threadIdx.x] = st[(b * 32 + threadIdx.x) * 2 + 1];
  }
  __syncthreads();
  for (int c = threadIdx.x; c < 320; c += 256) {
    int g = c / 10;
    float xv = xa[((long)b * 128 + pp) * 320 + c];
    xl[((long)b * 81 + pp) * 320 + c] = (xv - ms[g]) * rss[g] * sgb[c] + sgb[320 + c];
  }
}

// paste: Type-B channels (overlapping part_f/xa_f spans) full copy+add; else add-only
__global__ void k_paste(const float* __restrict__ gx, const float* __restrict__ bbox,
                        const float* __restrict__ xl, float* __restrict__ out) {
  int bc = blockIdx.x;
  int b = bc / 320;
  int c = bc - b * 320;
  __shared__ int sy[64], sx[64];
  __shared__ unsigned char my[64], mx[64];
  int x1b = (int)floorf(bbox[b * 4 + 0] * 64.f);
  int y1b = (int)floorf(bbox[b * 4 + 1] * 64.f);
  int x2b = max((int)floorf(bbox[b * 4 + 2] * 64.f), x1b + 1);
  int y2b = max((int)floorf(bbox[b * 4 + 3] * 64.f), y1b + 1);
  int t = threadIdx.x;
  if (t < 64) {
    int jy = t - y1b, oh = y2b - y1b;
    my[t] = (jy >= 0 && t < y2b) ? 1 : 0;
    sy[t] = my[t] ? min(jy * 9 / oh, 8) : 0;
    int jx = t - x1b, ow = x2b - x1b;
    mx[t] = (jx >= 0 && t < x2b) ? 1 : 0;
    sx[t] = mx[t] ? min(jx * 9 / ow, 8) : 0;
  }
  __syncthreads();
  size_t base = (size_t)bc * 4096;
  const float* xlb = xl + ((long)b * 81) * 320 + c;
  float4* o4 = (float4*)(out + base);
  bool typeB = (bc >= 2368 && bc < 4048) || (bc >= 9416 && bc < 9737);
  if (typeB) {
    const float4* g4 = (const float4*)(gx + base);
#pragma unroll
    for (int it = 0; it < 4; ++it) {
      int idx = it * 256 + t;
      int y = idx >> 4, x0 = (idx & 15) << 2;
      float4 v = g4[idx];
      if (my[y]) {
        const float* row = xlb + (long)sy[y] * 9 * 320;
        if (mx[x0 + 0]) v.x += row[(long)sx[x0 + 0] * 320];
        if (mx[x0 + 1]) v.y += row[(long)sx[x0 + 1] * 320];
        if (mx[x0 + 2]) v.z += row[(long)sx[x0 + 2] * 320];
        if (mx[x0 + 3]) v.w += row[(long)sx[x0 + 3] * 320];
      }
      o4[idx] = v;
    }
    return;
  }
  // add-only over bbox rows/quads (out already == gx there)
  int yH = min(y2b, 64);
  int xqL = x1b >> 2;
  int xqH = min((x2b + 3) >> 2, 16);
  int nxq = xqH - xqL;
  int nq = (yH - y1b) * nxq;
  for (int e = t; e < nq; e += 256) {
    int ry = y1b + e / nxq;
    int qx = xqL + (e - (e / nxq) * nxq);
    int idx = ry * 16 + qx;
    float4 v = o4[idx];
    int x0 = qx << 2;
    const float* row = xlb + (long)sy[ry] * 9 * 320;
    if (mx[x0 + 0]) v.x += row[(long)sx[x0 + 0] * 320];
    if (mx[x0 + 1]) v.y += row[(long)sx[x0 + 1] * 320];
    if (mx[x0 + 2]) v.z += row[(long)sx[x0 + 2] * 320];
    if (mx[x0 + 3]) v.w += row[(long)sx[x0 + 3] * 320];
    o4[idx] = v;
  }
}

// ---------------- launch ----------------

extern "C" void kernel_launch(void* const* d_in, const int* in_sizes, int n_in,
                              void* d_out, int out_size, void* d_ws, size_t ws_size,
                              hipStream_t stream) {
  const float* gx   = (const float*)d_in[0];
  const float* ctx  = (const float*)d_in[1];
  const float* ind  = (const float*)d_in[2];
  const float* bbox = (const float*)d_in[3];
  const int*   cond = (const int*)d_in[4];
  const float* ln_g = (const float*)d_in[5];
  const float* ln_b = (const float*)d_in[6];
  const float* cn_g = (const float*)d_in[7];
  const float* cn_b = (const float*)d_in[8];
  const float* Wq = (const float*)d_in[9];   const float* bq = (const float*)d_in[10];
  const float* Wk = (const float*)d_in[11];  const float* bk = (const float*)d_in[12];
  const float* Wv = (const float*)d_in[13];  const float* bv = (const float*)d_in[14];
  const float* Wsg = (const float*)d_in[15]; const float* bsg = (const float*)d_in[16];
  const float* Wsb = (const float*)d_in[17]; const float* bsb = (const float*)d_in[18];

  char* base = (char*)d_out;
  float* out = (float*)d_out;
  float* attn_out = out + (size_t)41943040;   // second output (B,81,256) fp32

  // arena inside first output region (167,772,160 B)
  u16* sel     = (u16*)(base + 0);            // [0, 16,777,216)
  u16* bvc     = (u16*)(base + 16777216);     // [16,777,216, 38,797,312)
  u16* cn2     = (u16*)(base + 38797312);     // [38,797,312, 72,351,744)
  u16* Aq2     = (u16*)(base + 72351744);     // [72,351,744, 78,643,200)
  float* part_f= (float*)(base + 38797312);   // overlay [38,797,312, 66,322,432)
  u16* k2      = (u16*)(base + 78643200);     // [78,643,200, 89,128,960)
  u16* q2      = (u16*)(base + 89128960);     // [89,128,960, 94,371,840)
  u16* attn_bf = (u16*)(base + 94371840);     // [94,371,840, 96,468,992)
  u16* ac_bf   = (u16*)(base + 96468992);     // [96,468,992, 104,857,600)
  u16* Wk2     = (u16*)(base + 108175360);    // [108,175,360, 109,748,224)
  u16* Wq2     = (u16*)(base + 109748224);    // [109,748,224, 110,239,744)
  u16* Wv_r    = (u16*)(base + 110239744);    // [110,239,744, 117,317,632) incl zpage @116,137,984
  u16* Wsgsb   = (u16*)(base + 117317632);    // [117,317,632, 129,114,112)
  float* partV = (float*)(base + 129114112);  // [129,114,112, 154,279,936)
  float* xa_f  = (float*)(base + 154279936);  // [154,279,936, 159,522,816)
  u16* zpage   = Wv_r + (size_t)320 * 9216;

  float* cmean = (float*)d_ws;            // 32768 f
  float* cnst  = cmean + 32768;           // 2048 f
  float* lnst  = cnst + 2048;             // 2048 f
  float* xast  = lnst + 2048;             // 2048 f
  float* roix  = xast + 2048;             // 829440 f
  float* xloc  = roix + 829440;           // [32][81][320] 829440 f

  // prep
  k_prep0<<<4096, 256, 0, stream>>>(ctx, cond, gx, bbox, Wk, Wq, Wv, Wsg, Wsb,
                                    cmean, cnst, roix, Wk2, Wq2, Wv_r, Wsgsb);
  k_prep1<<<3072, 256, 0, stream>>>(ctx, cmean, cnst, cn_g, cn_b, cond, sel, bvc, cn2,
                                    roix, lnst);
  k_aq2<<<6144, 256, 0, stream>>>(roix, lnst, ln_g, ln_b, ind, Aq2);

  // packed big GEMMs (full + narrow panels)
  k_gemms<<<896, 256, 0, stream>>>(cn2, Wk2, k2, bk, sel, Wv_r, zpage, partV,
                                   Aq2, Wq2, q2, bq);
  // packed mid: V sum+transpose | logits | out-copies (dead spans)
  k_mid<<<1408, 256, 0, stream>>>(partV, bv, bvc, q2, k2, attn_out, gx, out);
  k_softmax2<<<dim3(128, 32), 256, 0, stream>>>(attn_out, attn_bf);
  // packed attn GEMM: xa|ac | out-copies
  k_attn<<<1856, 256, 0, stream>>>(attn_bf, bvc, xa_f, ac_bf, gx, out);
  // packed post: xa stats | SGSB | out-copies
  k_post<<<1700, 256, 0, stream>>>(xa_f, xast, ac_bf, zpage, Wsgsb, part_f, gx, out);
  // fused sum+combine -> xloc | out-copies
  k_sum_sgsb<<<2848, 256, 0, stream>>>(part_f, (long)2688 * 640, bsg, bsb, xa_f, xast, xloc,
                                       gx, out);

  k_paste<<<10240, 256, 0, stream>>>(gx, bbox, xloc, out);
}

// Round 20
// 307.798 us; speedup vs baseline: 1.0727x; 1.0727x over previous
//
#include <hip/hip_runtime.h>
#include <hip/hip_bf16.h>

#define DINLINE __device__ __forceinline__

typedef short short8 __attribute__((ext_vector_type(8)));
typedef float f32x4 __attribute__((ext_vector_type(4)));
typedef unsigned short u16;

DINLINE u16 f2b(float f) {
  __hip_bfloat16 h = __float2bfloat16(f);
  return *reinterpret_cast<u16*>(&h);
}
DINLINE float b2f(u16 u) {
  __hip_bfloat16 h = *reinterpret_cast<__hip_bfloat16*>(&u);
  return __bfloat162float(h);
}

DINLINE void gload16(const u16* g, u16* l) {
  __builtin_amdgcn_global_load_lds((const __attribute__((address_space(1))) void*)g,
                                   (__attribute__((address_space(3))) void*)l, 16, 0, 0);
}

DINLINE void wave_red2(float& s, float& s2) {
  for (int o = 32; o > 0; o >>= 1) { s += __shfl_down(s, o); s2 += __shfl_down(s2, o); }
}

// ---------------- A-source functors ----------------

struct RowA {
  const u16* A; int physW;
  struct RS { const u16* base; };
  DINLINE RS row(long p) const { return { A + p * (long)physW }; }
  DINLINE const u16* ptr(const RS& rs, int kk) const { return rs.base + (kk << 6); }
};
struct TriA {  // [hi|lo] phys; logical role r = kk%3: (hi, lo, hi)
  const u16* A; int physW; int nhi;
  struct RS { const u16* base; };
  DINLINE RS row(long p) const { return { A + p * (long)physW }; }
  DINLINE const u16* ptr(const RS& rs, int kk) const {
    int c = (int)(((unsigned)kk * 171u) >> 9), r = kk - 3 * c;
    return rs.base + (((r == 1 ? nhi : 0) + c) << 6);
  }
};
struct ShiftVA {  // V conv rows over sel [b][256][1024]
  const u16* src; const u16* zp;
  struct RS { int y, x; const u16* bbase; };
  DINLINE RS row(long p) const {
    int b = (int)(p >> 8), ps = (int)p & 255;
    return { ps >> 4, ps & 15, src + ((long)b << 18) };
  }
  DINLINE const u16* ptr(const RS& rs, int kk) const {
    int c = (int)(((unsigned)kk * 57u) >> 9), s = kk - 9 * c;
    int sy = (s * 11) >> 5, sx = s - sy * 3;
    int yy = rs.y + sy - 1, xx = rs.x + sx - 1;
    bool ok = ((unsigned)yy < 16u) & ((unsigned)xx < 16u);
    return ok ? rs.bbase + (((yy << 4) + xx) << 10) + (c << 6) : zp;
  }
};
struct Shift9A {  // SGSB conv rows over ac [b][128][1024] (9x9 spatial)
  const u16* src; const u16* zp;
  struct RS { int y, x; const u16* bbase; int pin; };
  DINLINE RS row(long p) const {
    int pi = (int)p;
    int b = pi / 81, pp = pi - b * 81;
    int pin = pi < 2592 ? 1 : 0;
    if (b > 31) b = 31;
    return { pp / 9, pp % 9, src + ((long)b << 17), pin };
  }
  DINLINE const u16* ptr(const RS& rs, int kk) const {
    int c = (int)(((unsigned)kk * 57u) >> 9), s = kk - 9 * c;
    int sy = (s * 11) >> 5, sx = s - sy * 3;
    int yy = rs.y + sy - 1, xx = rs.x + sx - 1;
    bool ok = rs.pin && ((unsigned)yy < 9u) && ((unsigned)xx < 9u);
    return ok ? rs.bbase + ((yy * 9 + xx) << 10) + (c << 6) : zp;
  }
};

// ---------------- B-source functors ----------------

struct RowB {  // batch = by>>1 for 64-row tiles in 128-row batches
  const u16* B; int physW; long bstride;
  struct RS { const u16* base; };
  DINLINE RS row(int by, long j) const { return { B + ((long)(by >> 1) * bstride + j) * physW }; }
  DINLINE const u16* ptr(const RS& rs, int kk) const { return rs.base + (kk << 6); }
};
struct TriB {  // [hi|lo] phys; role r: (hi, hi, lo)
  const u16* B; int physW; int nhi; long bstride;
  struct RS { const u16* base; };
  DINLINE RS row(int by, long j) const { return { B + ((long)(by >> 1) * bstride + j) * physW }; }
  DINLINE const u16* ptr(const RS& rs, int kk) const {
    int c = (int)(((unsigned)kk * 171u) >> 9), r = kk - 3 * c;
    return rs.base + (((r == 2 ? nhi : 0) + c) << 6);
  }
};
struct ShiftWB {  // conv weights [N][9216] shift-major
  const u16* W;
  struct RS { const u16* base; };
  DINLINE RS row(int, long j) const { return { W + j * 9216 }; }
  DINLINE const u16* ptr(const RS& rs, int kk) const {
    int c = (int)(((unsigned)kk * 57u) >> 9), s = kk - 9 * c;
    return rs.base + (s << 10) + (c << 6);
  }
};

// ---------------- epilogues ----------------

struct EpiHiLo {
  u16* o; const float* bias;
  DINLINE void operator()(long p, int j, float v) const {
    v += bias[j];
    u16 hi = f2b(v), lo = f2b(v - b2f(hi));
    u16* q = o + p * 640 + j;
    q[0] = hi; q[320] = lo;
  }
};
struct EpiHiLoP {  // (part,p,j,v) for gemm128 direct; j>=320 is N-padding -> drop
  u16* o; const float* bias;
  DINLINE void operator()(int, long p, int j, float v) const {
    if (j >= 320) return;
    v += bias[j];
    u16 hi = f2b(v), lo = f2b(v - b2f(hi));
    u16* q = o + p * 640 + j;
    q[0] = hi; q[320] = lo;
  }
};
struct EpiLog {
  float* attn;
  DINLINE void operator()(long p, int j, float v) const {
    int b = (int)(p >> 7), i = (int)p & 127;
    if (i < 81) attn[((long)b * 81 + i) * 256 + j] = v;
  }
};
struct EpiXaAc {
  float* xa; u16* ac;
  DINLINE void operator()(long p, int j, float v) const {
    int b = (int)(p >> 7), i = (int)p & 127;
    if (j < 320) {
      xa[((long)b * 128 + i) * 320 + j] = v;
    } else {
      ac[((long)b * 128 + i) * 1024 + (j - 320)] = f2b(v);
    }
  }
};
struct EpiPart {
  float* buf; long pstride; int jw;
  DINLINE void operator()(int part, long p, int j, float v) const {
    buf[(long)part * pstride + p * (long)jw + j] = v;
  }
};

// ---------------- 64x64 4-wave pipelined MFMA GEMM body (lds: 16384 u16) ----------------

template <class AS, class BS, class EPI>
DINLINE void gemm_pipe_body(u16* lds, AS a, BS bsrc, int gy, int nch, EPI epi,
                            int subN, int bid) {
  const int q = subN >> 3, r8 = subN & 7;
  const int j8 = bid & 7, pos = bid >> 3;
  const int lid = (j8 < r8) ? j8 * (q + 1) + pos : r8 * (q + 1) + (j8 - r8) * q + pos;
  const int by = lid % gy, bx = lid / gy;

  const int tid = threadIdx.x;
  const int w = tid >> 6, lane = tid & 63;
  const int wm = w >> 1, wn = w & 1;
  const long p0 = (long)by * 64;
  const int j0 = bx * 64;

  const int r0 = tid >> 3;
  const int csw = (((lane & 7) ^ (lane >> 3)) << 3);
  auto rsA0 = a.row(p0 + r0);
  auto rsA1 = a.row(p0 + r0 + 32);
  auto rsB0 = bsrc.row(by, j0 + r0);
  auto rsB1 = bsrc.row(by, j0 + r0 + 32);
  u16* lA0 = lds + w * 512;
  u16* lA1 = lds + 2048 + w * 512;
  u16* lB0 = lds + 8192 + w * 512;
  u16* lB1 = lds + 8192 + 2048 + w * 512;

  f32x4 acc[2][2];
#pragma unroll
  for (int x = 0; x < 2; ++x)
#pragma unroll
    for (int y = 0; y < 2; ++y) acc[x][y] = (f32x4){0.f, 0.f, 0.f, 0.f};

  const int fr = lane & 15, fs = lane >> 4, fx = lane & 7;
  const int arow0 = (wm * 32 + fr) * 64;
  const int brow0 = (wn * 32 + fr) * 64;

  gload16(a.ptr(rsA0, 0) + csw, lA0);
  gload16(a.ptr(rsA1, 0) + csw, lA1);
  gload16(bsrc.ptr(rsB0, 0) + csw, lB0);
  gload16(bsrc.ptr(rsB1, 0) + csw, lB1);

  for (int kk = 0; kk < nch; ++kk) {
    const int cur = kk & 1;
    if (kk + 1 < nch) {
      const int nxt = cur ^ 1;
      gload16(a.ptr(rsA0, kk + 1) + csw, lA0 + nxt * 4096);
      gload16(a.ptr(rsA1, kk + 1) + csw, lA1 + nxt * 4096);
      gload16(bsrc.ptr(rsB0, kk + 1) + csw, lB0 + nxt * 4096);
      gload16(bsrc.ptr(rsB1, kk + 1) + csw, lB1 + nxt * 4096);
      asm volatile("s_waitcnt vmcnt(4)" ::: "memory");
    } else {
      asm volatile("s_waitcnt vmcnt(0)" ::: "memory");
    }
    __builtin_amdgcn_s_barrier();
    __builtin_amdgcn_sched_barrier(0);
    short8 af[2][2], bf[2][2];
#pragma unroll
    for (int fm = 0; fm < 2; ++fm)
#pragma unroll
      for (int kh = 0; kh < 2; ++kh) {
        int slot = ((((kh << 2) | fs) ^ fx) << 3);
        af[fm][kh] = *(const short8*)(lds + cur * 4096 + arow0 + fm * 1024 + slot);
      }
#pragma unroll
    for (int fn = 0; fn < 2; ++fn)
#pragma unroll
      for (int kh = 0; kh < 2; ++kh) {
        int slot = ((((kh << 2) | fs) ^ fx) << 3);
        bf[fn][kh] = *(const short8*)(lds + 8192 + cur * 4096 + brow0 + fn * 1024 + slot);
      }
#pragma unroll
    for (int kh = 0; kh < 2; ++kh)
#pragma unroll
      for (int fm = 0; fm < 2; ++fm)
#pragma unroll
        for (int fn = 0; fn < 2; ++fn)
          acc[fm][fn] = __builtin_amdgcn_mfma_f32_16x16x32_bf16(af[fm][kh], bf[fn][kh], acc[fm][fn], 0, 0, 0);
    __builtin_amdgcn_sched_barrier(0);
    __builtin_amdgcn_s_barrier();
  }

  const long ip = p0 + wm * 32 + fs * 4;
  const int jb = j0 + wn * 32 + fr;
#pragma unroll
  for (int fm = 0; fm < 2; ++fm)
#pragma unroll
    for (int fn = 0; fn < 2; ++fn)
#pragma unroll
      for (int rr = 0; rr < 4; ++rr)
        epi(ip + fm * 16 + rr, jb + fn * 16, acc[fm][fn][rr]);
}

// ------- 128xN 4-wave m97-structure MFMA GEMM body; tile N = NF*32 ----------

template <int NF, class AS, class BS, class EPI>
DINLINE void gemm128_body(u16* lds, AS a, BS bsrc, int gy, int gp, int nchw, EPI epi,
                          int subN, int bid, int j0base) {
  const int q = subN >> 3, r8 = subN & 7;
  const int j8 = bid & 7, pos = bid >> 3;
  const int lid = (j8 < r8) ? j8 * (q + 1) + pos : r8 * (q + 1) + (j8 - r8) * q + pos;
  const int gyp = gy * gp;
  const int bx = lid / gyp;
  const int rem = lid - bx * gyp;
  const int by = rem % gy;
  const int part = rem / gy;
  const int k0 = part * nchw;

  const int tid = threadIdx.x;
  const int w = tid >> 6, lane = tid & 63;
  const int wm = w >> 1, wn = w & 1;
  const long p0 = (long)by * 128;
  const int j0 = j0base + bx * (NF * 32);

  const int r0 = tid >> 3;
  const int csw = (((lane & 7) ^ (lane >> 3)) << 3);
  typename AS::RS rsA[4];
  typename BS::RS rsB[NF];
#pragma unroll
  for (int i = 0; i < 4; ++i) rsA[i] = a.row(p0 + r0 + 32 * i);
#pragma unroll
  for (int i = 0; i < NF; ++i) rsB[i] = bsrc.row(by, (long)j0 + r0 + 32 * i);

  f32x4 acc[4][NF];
#pragma unroll
  for (int x = 0; x < 4; ++x)
#pragma unroll
    for (int y = 0; y < NF; ++y) acc[x][y] = (f32x4){0.f, 0.f, 0.f, 0.f};

  const int fr = lane & 15, fs = lane >> 4, fx = lane & 7;

  for (int kk = 0; kk < nchw; ++kk) {
    __syncthreads();
#pragma unroll
    for (int i = 0; i < 4; ++i)
      gload16(a.ptr(rsA[i], k0 + kk) + csw, lds + (i * 32 + w * 8) * 64);
#pragma unroll
    for (int i = 0; i < NF; ++i)
      gload16(bsrc.ptr(rsB[i], k0 + kk) + csw, lds + 8192 + (i * 32 + w * 8) * 64);
    __syncthreads();
#pragma unroll
    for (int kh = 0; kh < 2; ++kh) {
      const int slot = ((((kh << 2) | fs) ^ fx) << 3);
      short8 af[4], bf[NF];
#pragma unroll
      for (int i = 0; i < 4; ++i)
        af[i] = *(const short8*)(lds + (wm * 64 + i * 16 + fr) * 64 + slot);
#pragma unroll
      for (int i = 0; i < NF; ++i)
        bf[i] = *(const short8*)(lds + 8192 + (wn * (NF * 16) + i * 16 + fr) * 64 + slot);
#pragma unroll
      for (int fm = 0; fm < 4; ++fm)
#pragma unroll
        for (int fn = 0; fn < NF; ++fn)
          acc[fm][fn] = __builtin_amdgcn_mfma_f32_16x16x32_bf16(af[fm], bf[fn], acc[fm][fn], 0, 0, 0);
    }
  }

  const long ip = p0 + wm * 64 + fs * 4;
  const int jb = j0 + wn * (NF * 16) + fr;
#pragma unroll
  for (int fm = 0; fm < 4; ++fm)
#pragma unroll
    for (int fn = 0; fn < NF; ++fn)
#pragma unroll
      for (int rr = 0; rr < 4; ++rr)
        epi(part, ip + fm * 16 + rr, jb + fn * 16, acc[fm][fn][rr]);
}

// ---------------- merged prep kernel 0: ctx_stats | roi | wprep ----------------
__global__ void k_prep0(const float* __restrict__ ctx, const int* __restrict__ cond,
                        const float* __restrict__ gx, const float* __restrict__ bbox,
                        const float* __restrict__ Wk, const float* __restrict__ Wq,
                        const float* __restrict__ Wv, const float* __restrict__ Wsg,
                        const float* __restrict__ Wsb,
                        float* __restrict__ cmean, float* __restrict__ stats,
                        float* __restrict__ roix, u16* __restrict__ oK, u16* __restrict__ oQ,
                        u16* __restrict__ Wv_r, u16* __restrict__ Wsgsb) {
  __shared__ float shf[4][2];
  __shared__ float cp[8][32];
  __shared__ float cm32[32];
  __shared__ int iy0[9], iy1[9], ix0[9], ix1[9];
  __shared__ float fly[9], flx[9];
  __shared__ u16 l[9216];
  int bid = blockIdx.x;
  int tid = threadIdx.x;

  if (bid < 1024) {
    int b = bid >> 5, g = bid & 31;
    const float* src = ctx + (size_t)b * 262144 + g * 32;
    int c = tid & 31, tg = tid >> 5;
    float cs = 0.f, s = 0.f, s2 = 0.f;
#pragma unroll 4
    for (int k = 0; k < 32; ++k) {
      int t = tg + k * 8;
      float v = src[(size_t)t * 1024 + c];
      cs += v; s += v; s2 += v * v;
    }
    cp[tg][c] = cs;
    wave_red2(s, s2);
    int lane = tid & 63, w = tid >> 6;
    if (lane == 0) { shf[w][0] = s; shf[w][1] = s2; }
    __syncthreads();
    if (tid < 32) {
      float colsum = 0.f;
#pragma unroll
      for (int k = 0; k < 8; ++k) colsum += cp[k][tid];
      float mv = colsum * (1.f / 256.f);
      cmean[b * 1024 + g * 32 + tid] = mv;
      cm32[tid] = mv;
    }
    __syncthreads();
    if (tid == 0) {
      float m, var;
      if (cond[b]) {
        float ts = shf[0][0] + shf[1][0] + shf[2][0] + shf[3][0];
        float ts2 = shf[0][1] + shf[1][1] + shf[2][1] + shf[3][1];
        m = ts * (1.f / 8192.f);
        var = ts2 * (1.f / 8192.f) - m * m;
      } else {
        float ms = 0.f, ms2 = 0.f;
#pragma unroll
        for (int k = 0; k < 32; ++k) { ms += cm32[k]; ms2 += cm32[k] * cm32[k]; }
        m = ms * (1.f / 32.f);
        var = ms2 * (1.f / 32.f) - m * m;
      }
      stats[bid * 2] = m;
      stats[bid * 2 + 1] = 1.f / sqrtf(var + 1e-6f);
    }
    return;
  }
  if (bid < 1056) {
    int b = bid - 1024;
    int t = tid;
    if (t < 9) {
      float x1 = bbox[b * 4 + 0], y1 = bbox[b * 4 + 1], x2 = bbox[b * 4 + 2], y2 = bbox[b * 4 + 3];
      float rw = fmaxf(x2 - x1, 1.f), rh = fmaxf(y2 - y1, 1.f);
      float ctr = ((float)t + 0.5f) / 9.0f;
      float yc = fminf(fmaxf(y1 + ctr * rh, 0.f), 63.f);
      int y0 = (int)floorf(yc);
      iy0[t] = y0; iy1[t] = min(y0 + 1, 63); fly[t] = yc - (float)y0;
      float xc = fminf(fmaxf(x1 + ctr * rw, 0.f), 63.f);
      int x0 = (int)floorf(xc);
      ix0[t] = x0; ix1[t] = min(x0 + 1, 63); flx[t] = xc - (float)x0;
    }
    __syncthreads();
    for (int idx = t; idx < 320 * 81; idx += 256) {
      int c = idx / 81, p = idx - c * 81;
      int py = p / 9, px = p - py * 9;
      const float* img = gx + ((size_t)b * 320 + c) * 4096;
      float ly = fly[py], lx = flx[px];
      float v00 = img[iy0[py] * 64 + ix0[px]];
      float v01 = img[iy0[py] * 64 + ix1[px]];
      float v10 = img[iy1[py] * 64 + ix0[px]];
      float v11 = img[iy1[py] * 64 + ix1[px]];
      roix[((size_t)b * 320 + c) * 81 + p] =
          v00 * (1.f - ly) * (1.f - lx) + v01 * (1.f - ly) * lx + v10 * ly * (1.f - lx) + v11 * ly * lx;
    }
    return;
  }
  int bid2 = bid - 1056;
  if (bid2 < 1536) {
    int i = bid2 * 256 + tid;
    int c = i >> 10, d = i & 1023;
    float v = (i < 327680) ? Wk[i] : 0.f;
    u16 hi = f2b(v), lo = f2b(v - b2f(hi));
    u16* p = oK + (size_t)c * 2048 + d;
    p[0] = hi; p[1024] = lo;
    return;
  }
  if (bid2 < 2016) {
    int i = (bid2 - 1536) * 256 + tid;
    if (i >= 122880) return;
    int c = i / 384, k = i - c * 384;
    float v = (k < 322) ? Wq[c * 322 + k] : 0.f;
    u16 hi = f2b(v), lo = f2b(v - b2f(hi));
    u16* p = oQ + (size_t)c * 768 + k;
    p[0] = hi; p[384] = lo;
    return;
  }
  int cc = bid2 - 2016;
  const float* src = nullptr; u16* dst;
  if (cc < 384) { dst = Wv_r + (size_t)cc * 9216; if (cc < 320) src = Wv + (size_t)cc * 9216; }
  else if (cc < 704) { src = Wsg + (size_t)(cc - 384) * 9216; dst = Wsgsb + (size_t)(cc - 384) * 9216; }
  else { src = Wsb + (size_t)(cc - 704) * 9216; dst = Wsgsb + (size_t)(320 + cc - 704) * 9216; }
  if (src == nullptr) {
    for (int i = tid; i < 9216; i += 256) dst[i] = 0;
    return;
  }
  for (int i = tid; i < 9216; i += 256) l[i] = f2b(src[i]);
  __syncthreads();
  for (int i = tid; i < 9216; i += 256) {
    int r = i >> 10, d = i & 1023;
    dst[i] = l[d * 9 + r];
  }
}

// ---------------- merged prep kernel 1: ctx_prep (0..2047) | stats810 (2048..3071) ------
__global__ __launch_bounds__(256) void k_prep1(
    const float* __restrict__ ctx, const float* __restrict__ cmean,
    const float* __restrict__ st, const float* __restrict__ cng,
    const float* __restrict__ cnb, const int* __restrict__ cond,
    u16* __restrict__ sel, u16* __restrict__ bvc, u16* __restrict__ cn2,
    const float* __restrict__ roix, float* __restrict__ lnst) {
  __shared__ u16 tile[64][66];
  __shared__ float sh[4][2];
  int bid = blockIdx.x;
  if (bid < 2048) {
    int b = bid >> 6;
    int d0 = ((bid >> 2) & 15) * 64;
    int t0 = (bid & 3) * 64;
    bool cf = cond[b] != 0;
#pragma unroll
    for (int q = 0; q < 16; ++q) {
      int idx = q * 256 + threadIdx.x;
      int r = idx >> 6, c = idx & 63;
      int t = t0 + r, d = d0 + c;
      float v = cf ? ctx[((size_t)b * 256 + t) * 1024 + d] : cmean[b * 1024 + d];
      u16 sv = f2b(v);
      sel[((size_t)b * 256 + t) * 1024 + d] = sv;
      tile[r][c] = sv;
      int gi = (b << 5) + (d >> 5);
      float nv = (v - st[gi * 2]) * st[gi * 2 + 1] * cng[d] + cnb[d];
      u16 hi = f2b(nv);
      u16 lo = f2b(nv - b2f(hi));
      size_t rbase = ((size_t)b * 256 + t) * 2048;
      cn2[rbase + d] = hi;
      cn2[rbase + 1024 + d] = lo;
    }
    __syncthreads();
#pragma unroll
    for (int q = 0; q < 16; ++q) {
      int idx = q * 256 + threadIdx.x;
      int r = idx >> 6, c = idx & 63;
      bvc[((size_t)b * 1344 + 320 + d0 + r) * 256 + t0 + c] = tile[c][r];
    }
    return;
  }
  int bg = bid - 2048;
  const float* p = roix + (size_t)bg * 810;
  float s = 0.f, s2 = 0.f;
  for (int i = threadIdx.x; i < 810; i += 256) { float v = p[i]; s += v; s2 += v * v; }
  wave_red2(s, s2);
  int lane = threadIdx.x & 63, w = threadIdx.x >> 6;
  if (lane == 0) { sh[w][0] = s; sh[w][1] = s2; }
  __syncthreads();
  if (threadIdx.x == 0) {
    s = sh[0][0] + sh[1][0] + sh[2][0] + sh[3][0];
    s2 = sh[0][1] + sh[1][1] + sh[2][1] + sh[3][1];
    float m = s * (1.f / 810.f);
    float var = s2 * (1.f / 810.f) - m * m;
    lnst[bg * 2] = m;
    lnst[bg * 2 + 1] = 1.f / sqrtf(var + 1e-6f);
  }
}

// Aq2 [4096][hi(384)|lo(384)]
__global__ void k_aq2(const float* __restrict__ roix, const float* __restrict__ st,
                      const float* __restrict__ lng, const float* __restrict__ lnb,
                      const float* __restrict__ ind, u16* __restrict__ o) {
  int i = blockIdx.x * 256 + threadIdx.x;
  if (i >= 32 * 128 * 384) return;
  int b = i / (128 * 384), rem = i - b * (128 * 384);
  int row = rem / 384, k = rem - row * 384;
  float v = 0.f;
  if (row < 81) {
    if (k < 320) {
      float x = roix[((size_t)b * 320 + k) * 81 + row];
      int gi = (b << 5) + k / 10;
      v = (x - st[gi * 2]) * st[gi * 2 + 1] * lng[k] + lnb[k];
    } else if (k < 322) v = ind[b * 2 + (k - 320)];
  }
  u16 hi = f2b(v);
  u16 lo = f2b(v - b2f(hi));
  u16* p = o + ((size_t)b * 128 + row) * 768 + k;
  p[0] = hi; p[384] = lo;
}

// -------- packed GEMMs: Kfull(0..127) | Knarrow(128..191) | Vfull(192..447) |
//          Vnarrow(448..575) | Q(576..895)
__global__ __launch_bounds__(256, 3) void k_gemms(
    const u16* __restrict__ cn2, const u16* __restrict__ Wk2, u16* __restrict__ k2,
    const float* __restrict__ bk,
    const u16* __restrict__ sel, const u16* __restrict__ Wv_r, const u16* __restrict__ zpage,
    float* __restrict__ partV,
    const u16* __restrict__ Aq2, const u16* __restrict__ Wq2, u16* __restrict__ q2,
    const float* __restrict__ bq) {
  __shared__ u16 lds[16384];
  int bid = blockIdx.x;
  if (bid < 128) {
    gemm128_body<4>(lds, TriA{cn2, 2048, 16}, TriB{Wk2, 2048, 16, 0}, 64, 1, 48,
                    EpiHiLoP{k2, bk}, 128, bid, 0);
  } else if (bid < 192) {
    gemm128_body<2>(lds, TriA{cn2, 2048, 16}, TriB{Wk2, 2048, 16, 0}, 64, 1, 48,
                    EpiHiLoP{k2, bk}, 64, bid - 128, 256);
  } else if (bid < 448) {
    gemm128_body<4>(lds, ShiftVA{sel, zpage}, ShiftWB{Wv_r}, 64, 2, 72,
                    EpiPart{partV, (long)8192 * 384, 384}, 256, bid - 192, 0);
  } else if (bid < 576) {
    gemm128_body<2>(lds, ShiftVA{sel, zpage}, ShiftWB{Wv_r}, 64, 2, 72,
                    EpiPart{partV, (long)8192 * 384, 384}, 128, bid - 448, 256);
  } else {
    gemm_pipe_body(lds, TriA{Aq2, 768, 6}, TriB{Wq2, 768, 6, 0}, 64, 18,
                   EpiHiLo{q2, bq}, 320, bid - 576);
  }
}

// ---------------- packed mid: sumv_t (0..639) | logits (640..895) ----------------
__global__ __launch_bounds__(256, 4) void k_mid(
    const float* __restrict__ partV, const float* __restrict__ bv, u16* __restrict__ bvc,
    const u16* __restrict__ q2, const u16* __restrict__ k2, float* __restrict__ attn) {
  __shared__ u16 lds[16384];
  int bid = blockIdx.x;
  if (bid < 640) {
    int b = bid / 20, rem = bid - b * 20;
    int t0 = (rem & 3) * 64, j0 = (rem >> 2) * 64;
    const long pstride = (long)8192 * 384;
#pragma unroll
    for (int q = 0; q < 16; ++q) {
      int idx = q * 256 + threadIdx.x;
      int r = idx >> 6, c = idx & 63;
      long p = (long)b * 256 + t0 + r;
      const float* src = partV + p * 384 + j0 + c;
      float v = src[0] + src[pstride] + bv[j0 + c];
      lds[r * 66 + c] = f2b(v);
    }
    __syncthreads();
#pragma unroll
    for (int q = 0; q < 16; ++q) {
      int idx = q * 256 + threadIdx.x;
      int r = idx >> 6, c = idx & 63;
      bvc[((long)b * 1344 + j0 + r) * 256 + t0 + c] = lds[c * 66 + r];
    }
    return;
  }
  gemm_pipe_body(lds, TriA{q2, 640, 5}, TriB{k2, 640, 5, 256}, 64, 15,
                 EpiLog{attn}, 256, bid - 640);
}

__global__ void k_softmax2(float* __restrict__ attn, u16* __restrict__ attn_bf) {
  int i = blockIdx.x, b = blockIdx.y;
  int t = threadIdx.x;
  if (i >= 81) { attn_bf[((size_t)b * 128 + i) * 256 + t] = 0; return; }
  float* p = attn + ((size_t)b * 81 + i) * 256;
  float v = p[t];
  float m = v;
  for (int o = 32; o > 0; o >>= 1) m = fmaxf(m, __shfl_down(m, o));
  __shared__ float sm[4], ss[4];
  if ((t & 63) == 0) sm[t >> 6] = m;
  __syncthreads();
  m = fmaxf(fmaxf(sm[0], sm[1]), fmaxf(sm[2], sm[3]));
  float e = expf(v - m);
  float s = e;
  for (int o = 32; o > 0; o >>= 1) s += __shfl_down(s, o);
  if ((t & 63) == 0) ss[t >> 6] = s;
  __syncthreads();
  s = ss[0] + ss[1] + ss[2] + ss[3];
  float r = e / s;
  p[t] = r;
  attn_bf[((size_t)b * 128 + i) * 256 + t] = f2b(r);
}

// standalone 64^2 GEMM kernel (xa|ac)
template <class AS, class BS, class EPI>
__global__ __launch_bounds__(256, 4) void gemm_pipe(AS a, BS bsrc, int gy, int nch, EPI epi) {
  __shared__ u16 lds[16384];
  gemm_pipe_body(lds, a, bsrc, gy, nch, epi, gridDim.x, blockIdx.x);
}

// ---------------- packed post: stats_xa (0..1023) | SGSB gemm128 (1024..1443) -------
__global__ __launch_bounds__(256, 3) void k_post(
    const float* __restrict__ xa, float* __restrict__ xast,
    const u16* __restrict__ ac_bf, const u16* __restrict__ zpage,
    const u16* __restrict__ Wsgsb, float* __restrict__ part_f) {
  __shared__ u16 lds[16384];
  int bid = blockIdx.x;
  if (bid < 1024) {
    int b = bid >> 5, g = bid & 31;
    float s = 0.f, s2 = 0.f;
    for (int e = threadIdx.x; e < 810; e += 256) {
      int i = e / 10, cc = e - i * 10;
      float v = xa[((long)b * 128 + i) * 320 + g * 10 + cc];
      s += v; s2 += v * v;
    }
    wave_red2(s, s2);
    float* sh = (float*)lds;
    int lane = threadIdx.x & 63, w = threadIdx.x >> 6;
    if (lane == 0) { sh[w * 2] = s; sh[w * 2 + 1] = s2; }
    __syncthreads();
    if (threadIdx.x == 0) {
      s = sh[0] + sh[2] + sh[4] + sh[6];
      s2 = sh[1] + sh[3] + sh[5] + sh[7];
      float m = s * (1.f / 810.f);
      float var = s2 * (1.f / 810.f) - m * m;
      xast[bid * 2] = m;
      xast[bid * 2 + 1] = 1.f / sqrtf(var + 1e-5f);
    }
    return;
  }
  gemm128_body<4>(lds, Shift9A{ac_bf, zpage}, ShiftWB{Wsgsb}, 21, 4, 36,
                  EpiPart{part_f, (long)2688 * 640, 640}, 420, bid - 1024, 0);
}

// fused SGSB sum + bias + gn(xa)*sg + sb -> xloc [b][81][320]
__global__ void k_sum_sgsb(const float* __restrict__ buf, long pstride,
                           const float* __restrict__ bsg, const float* __restrict__ bsb,
                           const float* __restrict__ xa, const float* __restrict__ st,
                           float* __restrict__ xl) {
  __shared__ float sgb[640];
  __shared__ float ms[32], rss[32];
  long p = blockIdx.x;
  int b = (int)(p / 81), pp = (int)(p - (long)b * 81);
  const float* src = buf + p * 640;
  for (int j = threadIdx.x; j < 640; j += 256) {
    float v = 0.f;
#pragma unroll
    for (int t = 0; t < 4; ++t) v += src[t * pstride + j];
    sgb[j] = v + (j < 320 ? bsg[j] : bsb[j - 320]);
  }
  if (threadIdx.x < 32) {
    ms[threadIdx.x] = st[(b * 32 + threadIdx.x) * 2];
    rss[threadIdx.x] = st[(b * 32 + threadIdx.x) * 2 + 1];
  }
  __syncthreads();
  for (int c = threadIdx.x; c < 320; c += 256) {
    int g = c / 10;
    float xv = xa[((long)b * 128 + pp) * 320 + c];
    xl[((long)b * 81 + pp) * 320 + c] = (xv - ms[g]) * rss[g] * sgb[c] + sgb[320 + c];
  }
}

// paste reading xloc [b][81][320]
__global__ void k_paste(const float* __restrict__ gx, const float* __restrict__ bbox,
                        const float* __restrict__ xl, float* __restrict__ out) {
  int bc = blockIdx.x;
  int b = bc / 320;
  int c = bc - b * 320;
  __shared__ int sy[64], sx[64];
  __shared__ unsigned char my[64], mx[64];
  int x1b = (int)floorf(bbox[b * 4 + 0] * 64.f);
  int y1b = (int)floorf(bbox[b * 4 + 1] * 64.f);
  int x2b = max((int)floorf(bbox[b * 4 + 2] * 64.f), x1b + 1);
  int y2b = max((int)floorf(bbox[b * 4 + 3] * 64.f), y1b + 1);
  int t = threadIdx.x;
  if (t < 64) {
    int jy = t - y1b, oh = y2b - y1b;
    my[t] = (jy >= 0 && t < y2b) ? 1 : 0;
    sy[t] = my[t] ? min(jy * 9 / oh, 8) : 0;
    int jx = t - x1b, ow = x2b - x1b;
    mx[t] = (jx >= 0 && t < x2b) ? 1 : 0;
    sx[t] = mx[t] ? min(jx * 9 / ow, 8) : 0;
  }
  __syncthreads();
  size_t base = (size_t)bc * 4096;
  const float* xlb = xl + ((long)b * 81) * 320 + c;
  const float4* g4 = (const float4*)(gx + base);
  float4* o4 = (float4*)(out + base);
#pragma unroll
  for (int it = 0; it < 4; ++it) {
    int idx = it * 256 + t;
    int y = idx >> 4, x0 = (idx & 15) << 2;
    float4 v = g4[idx];
    if (my[y]) {
      const float* row = xlb + (long)sy[y] * 9 * 320;
      if (mx[x0 + 0]) v.x += row[(long)sx[x0 + 0] * 320];
      if (mx[x0 + 1]) v.y += row[(long)sx[x0 + 1] * 320];
      if (mx[x0 + 2]) v.z += row[(long)sx[x0 + 2] * 320];
      if (mx[x0 + 3]) v.w += row[(long)sx[x0 + 3] * 320];
    }
    o4[idx] = v;
  }
}

// ---------------- launch ----------------

extern "C" void kernel_launch(void* const* d_in, const int* in_sizes, int n_in,
                              void* d_out, int out_size, void* d_ws, size_t ws_size,
                              hipStream_t stream) {
  const float* gx   = (const float*)d_in[0];
  const float* ctx  = (const float*)d_in[1];
  const float* ind  = (const float*)d_in[2];
  const float* bbox = (const float*)d_in[3];
  const int*   cond = (const int*)d_in[4];
  const float* ln_g = (const float*)d_in[5];
  const float* ln_b = (const float*)d_in[6];
  const float* cn_g = (const float*)d_in[7];
  const float* cn_b = (const float*)d_in[8];
  const float* Wq = (const float*)d_in[9];   const float* bq = (const float*)d_in[10];
  const float* Wk = (const float*)d_in[11];  const float* bk = (const float*)d_in[12];
  const float* Wv = (const float*)d_in[13];  const float* bv = (const float*)d_in[14];
  const float* Wsg = (const float*)d_in[15]; const float* bsg = (const float*)d_in[16];
  const float* Wsb = (const float*)d_in[17]; const float* bsb = (const float*)d_in[18];

  char* base = (char*)d_out;
  float* out = (float*)d_out;
  float* attn_out = out + (size_t)41943040;   // second output (B,81,256) fp32

  // arena inside first output region (167,772,160 B), fully overwritten by k_paste
  u16* sel     = (u16*)(base + 0);            // [0, 16,777,216)
  u16* bvc     = (u16*)(base + 16777216);     // [16,777,216, 38,797,312)
  u16* cn2     = (u16*)(base + 38797312);     // [38,797,312, 72,351,744)
  u16* Aq2     = (u16*)(base + 72351744);     // [72,351,744, 78,643,200)
  float* part_f= (float*)(base + 38797312);   // SGSB partials overlay (cn2+Aq2 dead by then)
  u16* k2      = (u16*)(base + 78643200);     // [78,643,200, 89,128,960)
  u16* q2      = (u16*)(base + 89128960);     // [89,128,960, 94,371,840)
  u16* attn_bf = (u16*)(base + 94371840);     // [94,371,840, 96,468,992)
  u16* ac_bf   = (u16*)(base + 96468992);     // [96,468,992, 104,857,600)
  u16* Wk2     = (u16*)(base + 108175360);    // [108,175,360, 109,748,224)
  u16* Wq2     = (u16*)(base + 109748224);    // [109,748,224, 110,239,744)
  u16* Wv_r    = (u16*)(base + 110239744);    // [110,239,744, 117,317,632)
  u16* Wsgsb   = (u16*)(base + 117317632);    // [117,317,632, 129,114,112)
  float* partV = (float*)(base + 129114112);  // [129,114,112, 154,279,936)
  float* xa_f  = (float*)(base + 154279936);  // [154,279,936, 159,522,816)
  u16* zpage   = Wv_r + (size_t)320 * 9216;   // 64 zero rows of Wv_r

  float* cmean = (float*)d_ws;            // 32768 f
  float* cnst  = cmean + 32768;           // 2048 f
  float* lnst  = cnst + 2048;             // 2048 f
  float* xast  = lnst + 2048;             // 2048 f
  float* roix  = xast + 2048;             // 829440 f
  float* xloc  = roix + 829440;           // [32][81][320] 829440 f

  // prep
  k_prep0<<<4096, 256, 0, stream>>>(ctx, cond, gx, bbox, Wk, Wq, Wv, Wsg, Wsb,
                                    cmean, cnst, roix, Wk2, Wq2, Wv_r, Wsgsb);
  k_prep1<<<3072, 256, 0, stream>>>(ctx, cmean, cnst, cn_g, cn_b, cond, sel, bvc, cn2,
                                    roix, lnst);
  k_aq2<<<6144, 256, 0, stream>>>(roix, lnst, ln_g, ln_b, ind, Aq2);

  // packed big GEMMs (full + narrow panels, no pad FLOPs)
  k_gemms<<<896, 256, 0, stream>>>(cn2, Wk2, k2, bk, sel, Wv_r, zpage, partV,
                                   Aq2, Wq2, q2, bq);
  // packed mid: V sum+bias+transpose -> bvc | logits -> attn_out
  k_mid<<<896, 256, 0, stream>>>(partV, bv, bvc, q2, k2, attn_out);
  k_softmax2<<<dim3(128, 32), 256, 0, stream>>>(attn_out, attn_bf);
  // fused xa|ac = attn @ [v; ctx]: per-batch [128][256] x bvc[1344][256]
  gemm_pipe<<<1344, 256, 0, stream>>>(RowA{attn_bf, 256}, RowB{bvc, 256, 1344},
                                      64, 4, EpiXaAc{xa_f, ac_bf});
  // packed post: xa group stats | SGSB conv (split-K=4 -> part_f)
  k_post<<<1444, 256, 0, stream>>>(xa_f, xast, ac_bf, zpage, Wsgsb, part_f);
  // fused sum + bias + combine -> xloc
  k_sum_sgsb<<<2592, 256, 0, stream>>>(part_f, (long)2688 * 640, bsg, bsb, xa_f, xast, xloc);

  k_paste<<<10240, 256, 0, stream>>>(gx, bbox, xloc, out);
}